// Round 5
// baseline (456.299 us; speedup 1.0000x reference)
//
#include <hip/hip_runtime.h>
#include <cstdint>
#include <cstddef>

#define BB 16
#define NN 8192
#define DD 384
#define HH 128
#define KK 8
#define DEG 16

typedef short bf8_t __attribute__((ext_vector_type(8)));
typedef float f4_t __attribute__((ext_vector_type(4)));

typedef const __attribute__((address_space(1))) unsigned char* gcp_t;
typedef __attribute__((address_space(3))) unsigned char* lcp_t;

__device__ __forceinline__ void glds16(const void* g, void* l) {
  __builtin_amdgcn_global_load_lds((gcp_t)g, (lcp_t)l, 16, 0, 0);
}

__device__ __forceinline__ unsigned short f2bf(float f) {
  unsigned int u = __float_as_uint(f);
  u += 0x7FFFu + ((u >> 16) & 1u);   // RNE
  return (unsigned short)(u >> 16);
}

__device__ __forceinline__ bf8_t pack8(float4 f0, float4 f1) {
  union { unsigned short us[8]; bf8_t v; } pk;
  pk.us[0] = f2bf(f0.x); pk.us[1] = f2bf(f0.y);
  pk.us[2] = f2bf(f0.z); pk.us[3] = f2bf(f0.w);
  pk.us[4] = f2bf(f1.x); pk.us[5] = f2bf(f1.y);
  pk.us[6] = f2bf(f1.z); pk.us[7] = f2bf(f1.w);
  return pk.v;
}

// ---------------------------------------------------------------------------
// Kprep: (a) fold q@W[384:,:]+bias into per-batch base vectors;
// (b) transpose+convert W1[:384]/P1[:384] to bf16, stored PRE-SWIZZLED and
// K-sixth'd for global_load_lds staging; (c) zero normsq.
// ---------------------------------------------------------------------------
__global__ __launch_bounds__(256) void kprep(
    const float* __restrict__ q, const float* __restrict__ W1,
    const float* __restrict__ b1, const float* __restrict__ P1,
    const float* __restrict__ pb1,
    unsigned short* __restrict__ W1t, unsigned short* __restrict__ P1t,
    float* __restrict__ base1, float* __restrict__ baseP,
    float* __restrict__ normsq)
{
  int blk = blockIdx.x, t = threadIdx.x;
  if (blk < 32) {
    int b = blk >> 1, net = blk & 1;
    const float* W = (net ? P1 : W1) + (size_t)DD * HH;   // q-half rows
    const float* qb = q + b * DD;
    int h = t & 127, half = t >> 7;
    int d0 = half * 192;
    float a0 = 0.f, a1 = 0.f, a2 = 0.f, a3 = 0.f;
    for (int d = d0; d < d0 + 192; d += 4) {
      a0 = fmaf(qb[d],     W[(size_t)d * HH + h],       a0);
      a1 = fmaf(qb[d + 1], W[(size_t)(d + 1) * HH + h], a1);
      a2 = fmaf(qb[d + 2], W[(size_t)(d + 2) * HH + h], a2);
      a3 = fmaf(qb[d + 3], W[(size_t)(d + 3) * HH + h], a3);
    }
    __shared__ float red[256];
    red[t] = (a0 + a1) + (a2 + a3);
    __syncthreads();
    if (t < 128) {
      float tot = red[t] + red[t + 128] + (net ? pb1[h] : b1[h]);
      (net ? baseP : base1)[b * HH + h] = tot;
    }
  } else {
    int e = (blk - 32) * 3072 + t;   // 32 blocks x 3072 = 2*49152 elems
    for (int it = 0; it < 12; ++it, e += 256) {
      int net = e / 49152;
      int r = e - net * 49152;
      int d = r >> 7;          // 0..383
      int h = r & 127;
      float v = (net ? P1 : W1)[d * HH + h];
      int ph = d >> 6;         // K-sixth 0..5
      int rem = d & 63;
      int cb = rem >> 3, wi = rem & 7;
      int c = cb ^ (h & 7);
      (net ? P1t : W1t)[ph * 8192 + h * 64 + c * 8 + wi] = f2bf(v);
    }
    if (blk == 32 && t < BB) normsq[t] = 0.f;
  }
}

// ---------------------------------------------------------------------------
// Kgemm (unchanged from round 4): K-sixth dbuf staging via global_load_lds,
// depth-1 A prefetch, ~116 total regs under __launch_bounds__(512,4).
// ---------------------------------------------------------------------------
__global__ __launch_bounds__(512, 4) void kgemm(
    const float* __restrict__ emb,
    const unsigned short* __restrict__ W1t, const unsigned short* __restrict__ P1t,
    const float* __restrict__ base1, const float* __restrict__ baseP,
    const float* __restrict__ W2, const float* __restrict__ b2,
    const float* __restrict__ P2, const float* __restrict__ pb2,
    float* __restrict__ rawamps, float* __restrict__ pslogit)
{
  __shared__ __align__(16) unsigned short sB[2][128 * 64];   // 2 x 16 KB
  __shared__ float sW2a[128 * 9];
  __shared__ float sBase[128];
  __shared__ float sP2[128];
  __shared__ float sB2[8];

  const int g = blockIdx.x;
  const int slot = g & 7;
  const int net = (g >> 3) & 1;
  const int wid = (g >> 4) * 8 + slot;       // 0..511
  const int b = wid >> 5;
  const int rowbase = (wid & 31) * 256;

  const int t = threadIdx.x;
  const int w = t >> 6, lane = t & 63, q = lane >> 4, ln = lane & 15;
  const int fl = ln & 7;                     // read-side swizzle key

  const unsigned short* Wsw = net ? P1t : W1t;

  // stage sixth 0 into buffer 0 (2 x 1KB per wave)
  {
    const unsigned short* src = Wsw + w * 512 + lane * 8;
    char* dst = (char*)&sB[0][0] + w * 1024;
    glds16(src,        dst);
    glds16(src + 4096, dst + 8192);
  }
  if (t < 128) sBase[t] = (net ? baseP : base1)[b * HH + t];
  if (net == 0) {
    for (int e = t; e < HH * KK; e += 512) {
      int h = e >> 3, kk = e & 7;
      sW2a[h * 9 + kk] = W2[e];
    }
    if (t < 8) sB2[t] = b2[t];
  } else if (t >= 128 && t < 256) {
    sP2[t - 128] = P2[t - 128];
  }

  const float* ar0 = emb + (size_t)(b * NN + rowbase + w * 32 + ln) * DD + q * 8;
  const float* ar1 = ar0 + (size_t)16 * DD;
  float4 pf[4];
  pf[0] = ((const float4*)ar0)[0]; pf[1] = ((const float4*)ar0)[1];
  pf[2] = ((const float4*)ar1)[0]; pf[3] = ((const float4*)ar1)[1];

  f4_t acc[2][8];
  f4_t zero = {0.f, 0.f, 0.f, 0.f};
#pragma unroll
  for (int i = 0; i < 8; ++i) { acc[0][i] = zero; acc[1][i] = zero; }

  __syncthreads();   // sixth 0 staged (barrier drains vmcnt)

#pragma unroll
  for (int ph = 0; ph < 6; ++ph) {
    if (ph < 5) {    // issue next-sixth staging; in flight across 2 j-steps
      const unsigned short* src = Wsw + (ph + 1) * 8192 + w * 512 + lane * 8;
      char* dst = (char*)&sB[0][0] + ((ph + 1) & 1) * 16384 + w * 1024;
      glds16(src,        dst);
      glds16(src + 4096, dst + 8192);
    }
    const char* bbase = (const char*)&sB[0][0] + (ph & 1) * 16384;
#pragma unroll
    for (int jl = 0; jl < 2; ++jl) {
      const int j = ph * 2 + jl;
      bf8_t af0 = pack8(pf[0], pf[1]);
      bf8_t af1 = pack8(pf[2], pf[3]);
      if (j + 1 < 12) {   // depth-1 A prefetch: j+1 in flight under 16 MFMAs
        const float* p0 = ar0 + (j + 1) * 32;
        const float* p1 = ar1 + (j + 1) * 32;
        pf[0] = ((const float4*)p0)[0]; pf[1] = ((const float4*)p0)[1];
        pf[2] = ((const float4*)p1)[0]; pf[3] = ((const float4*)p1)[1];
      }
      const int cb = jl * 4 + q;
#pragma unroll
      for (int ct = 0; ct < 8; ++ct) {
        const int h = ct * 16 + ln;
        bf8_t bf = *(const bf8_t*)(bbase + h * 128 + ((cb ^ fl) << 4));
        acc[0][ct] = __builtin_amdgcn_mfma_f32_16x16x32_bf16(af0, bf, acc[0][ct], 0, 0, 0);
        acc[1][ct] = __builtin_amdgcn_mfma_f32_16x16x32_bf16(af1, bf, acc[1][ct], 0, 0, 0);
      }
    }
    if (ph < 5) __syncthreads();
  }

  const float pb2v = pb2[0];
#pragma unroll
  for (int grp = 0; grp < 2; ++grp) {
#pragma unroll
    for (int r = 0; r < 4; ++r) {
      const int grow = rowbase + w * 32 + grp * 16 + q * 4 + r;
      if (net == 0) {
        float s[8];
#pragma unroll
        for (int kk = 0; kk < 8; ++kk) s[kk] = 0.f;
#pragma unroll
        for (int ct = 0; ct < 8; ++ct) {
          int col = ct * 16 + ln;
          float h1 = fmaxf(acc[grp][ct][r] + sBase[col], 0.f);
#pragma unroll
          for (int kk = 0; kk < 8; ++kk) s[kk] = fmaf(h1, sW2a[col * 9 + kk], s[kk]);
        }
#pragma unroll
        for (int off = 1; off < 16; off <<= 1)
#pragma unroll
          for (int kk = 0; kk < 8; ++kk) s[kk] += __shfl_xor(s[kk], off, 64);
        if (ln == 0) {
          float4 o0, o1;
          o0.x = s[0] + sB2[0]; o0.y = s[1] + sB2[1];
          o0.z = s[2] + sB2[2]; o0.w = s[3] + sB2[3];
          o1.x = s[4] + sB2[4]; o1.y = s[5] + sB2[5];
          o1.z = s[6] + sB2[6]; o1.w = s[7] + sB2[7];
          float4* dst = (float4*)(rawamps + (size_t)(b * NN + grow) * KK);
          dst[0] = o0; dst[1] = o1;
        }
      } else {
        float ps = 0.f;
#pragma unroll
        for (int ct = 0; ct < 8; ++ct) {
          int col = ct * 16 + ln;
          float hp = fmaxf(acc[grp][ct][r] + sBase[col], 0.f);
          ps = fmaf(hp, sP2[col], ps);
        }
#pragma unroll
        for (int off = 1; off < 16; off <<= 1) ps += __shfl_xor(ps, off, 64);
        if (ln == 0) pslogit[b * NN + grow] = ps + pb2v;
      }
    }
  }
}

// ---------------------------------------------------------------------------
// applyscale: ampsP[k][gnode] = raw[node][k] * (1 + sigmoid(psl) + label),
// k-major float planes (32 KB per (b,k)) — the LDS staging unit for sdiff.
// ---------------------------------------------------------------------------
__global__ __launch_bounds__(256) void applyscale(
    const float* __restrict__ raw, const float* __restrict__ psl,
    const int* __restrict__ lab, float* __restrict__ ampsP)
{
  int node = blockIdx.x * 256 + threadIdx.x;   // global node 0..131071
  float sc = 1.f + 1.f / (1.f + __expf(-psl[node])) + (float)lab[node];
  const float4* r = (const float4*)(raw + (size_t)node * KK);
  float4 v0 = r[0], v1 = r[1];
  const int BN = BB * NN;
  ampsP[0 * BN + node] = v0.x * sc;
  ampsP[1 * BN + node] = v0.y * sc;
  ampsP[2 * BN + node] = v0.z * sc;
  ampsP[3 * BN + node] = v0.w * sc;
  ampsP[4 * BN + node] = v1.x * sc;
  ampsP[5 * BN + node] = v1.y * sc;
  ampsP[6 * BN + node] = v1.z * sc;
  ampsP[7 * BN + node] = v1.w * sc;
}

// ---------------------------------------------------------------------------
// sdiff: ALL THREE diffusion steps fused, per (batch, k) plane, entirely in
// LDS. sAmp (32 KB, read-only amps plane) + sSt (32 KB, evolving state).
//   u1 = S(amps); m1 = u1*amps; u2 = S(m1); m2 = u2*amps; u3 = S(m2)
// (uniform state0 factor cancels in the final normalization). Gathers are
// ds_read_b32 from a 32 KB plane — no global round-trips between steps,
// no L2 thrash (round-4 lesson: random 32 B global gathers with outputs
// competing for the same L2 ran at L3 latency). nbr re-read per step from
// L2. 4 barriers total. Final step writes the u3 plane + norm partial.
// __launch_bounds__(1024,4): 128-reg cap, est ~80 live, no spills.
// ---------------------------------------------------------------------------
__global__ __launch_bounds__(1024, 4) void sdiff(
    const int* __restrict__ nbr, const float* __restrict__ ampsP,
    float* __restrict__ u3P, float* __restrict__ normsq)
{
  __shared__ float sAmp[NN];   // 32 KB
  __shared__ float sSt[NN];    // 32 KB
  const int g = blockIdx.x;    // 128 blocks
  const int b = g >> 3;
  const int k = g & 7;
  const int t = threadIdx.x;   // 0..1023
  const int BN = BB * NN;

  {
    const float4* p4 = (const float4*)(ampsP + (size_t)k * BN + (size_t)b * NN);
    float4* s4 = (float4*)sAmp;
    s4[t] = p4[t];
    s4[t + 1024] = p4[t + 1024];
  }
  const int* nbase = nbr + (size_t)b * NN * DEG;
  __syncthreads();

  float res[8];

#define GSTEP(SRC)                                                         \
  _Pragma("unroll")                                                        \
  for (int i = 0; i < 8; ++i) {                                            \
    const int n = i * 1024 + t;                                            \
    const int4* np = (const int4*)(nbase + (size_t)n * DEG);               \
    int4 q0 = np[0], q1 = np[1], q2 = np[2], q3 = np[3];                   \
    float a = SRC[q0.x] + SRC[q0.y] + SRC[q0.z] + SRC[q0.w]                \
            + SRC[q1.x] + SRC[q1.y] + SRC[q1.z] + SRC[q1.w]                \
            + SRC[q2.x] + SRC[q2.y] + SRC[q2.z] + SRC[q2.w]                \
            + SRC[q3.x] + SRC[q3.y] + SRC[q3.z] + SRC[q3.w];               \
    res[i] = a;                                                            \
  }

  // step 1: u1 = S(amps), m1 = u1*amps  (sSt untouched by gathers -> no
  // pre-write barrier needed)
  GSTEP(sAmp)
#pragma unroll
  for (int i = 0; i < 8; ++i) sSt[i * 1024 + t] = res[i] * sAmp[i * 1024 + t];
  __syncthreads();

  // step 2: u2 = S(m1), m2 = u2*amps  (gather-all, barrier, then overwrite)
  GSTEP(sSt)
  __syncthreads();
#pragma unroll
  for (int i = 0; i < 8; ++i) sSt[i * 1024 + t] = res[i] * sAmp[i * 1024 + t];
  __syncthreads();

  // step 3: u3 = S(m2) -> global plane + norm partial
  GSTEP(sSt)
#undef GSTEP
  float* oplane = u3P + (size_t)k * BN + (size_t)b * NN;
  float ss = 0.f;
#pragma unroll
  for (int i = 0; i < 8; ++i) {
    oplane[i * 1024 + t] = res[i];
    ss = fmaf(res[i], res[i], ss);
  }
#pragma unroll
  for (int o = 1; o < 64; o <<= 1) ss += __shfl_xor(ss, o, 64);
  if ((t & 63) == 0) atomicAdd(&normsq[b], ss);
}

__global__ __launch_bounds__(256) void fout(
    const float* __restrict__ u3P, const float* __restrict__ normsq,
    float* __restrict__ out)
{
  int node = blockIdx.x * 256 + threadIdx.x;   // global node
  float ns = normsq[node >> 13];
  float inv = ns > 0.f ? rsqrtf(ns) : 1.f;
  const int BN = BB * NN;
  float s = fabsf(u3P[0 * BN + node]) + fabsf(u3P[1 * BN + node])
          + fabsf(u3P[2 * BN + node]) + fabsf(u3P[3 * BN + node])
          + fabsf(u3P[4 * BN + node]) + fabsf(u3P[5 * BN + node])
          + fabsf(u3P[6 * BN + node]) + fabsf(u3P[7 * BN + node]);
  out[node] = s * inv;
}

extern "C" void kernel_launch(void* const* d_in, const int* in_sizes, int n_in,
                              void* d_out, int out_size, void* d_ws, size_t ws_size,
                              hipStream_t stream) {
  const float* q   = (const float*)d_in[0];
  const float* emb = (const float*)d_in[1];
  const int*   nbr = (const int*)d_in[2];
  const int*   lab = (const int*)d_in[3];
  const float* W1  = (const float*)d_in[4];
  const float* b1  = (const float*)d_in[5];
  const float* W2  = (const float*)d_in[6];
  const float* b2  = (const float*)d_in[7];
  const float* P1  = (const float*)d_in[8];
  const float* pb1 = (const float*)d_in[9];
  const float* P2  = (const float*)d_in[10];
  const float* pb2 = (const float*)d_in[11];
  float* out = (float*)d_out;

  const size_t NK = (size_t)BB * NN * KK;     // 1,048,576 floats (4 MB)
  float* ws     = (float*)d_ws;
  float* buf0   = ws;                         // raw amps (node-major)
  float* buf1   = buf0 + NK;                  // ampsP (k-major planes)
  float* buf2   = buf1 + NK;                  // u3P (k-major planes)
  float* psl    = buf2 + NK;                  // 131072
  float* base1  = psl + (size_t)BB * NN;
  float* baseP  = base1 + BB * HH;
  float* normsq = baseP + BB * HH;
  unsigned short* W1t = (unsigned short*)(normsq + 16);
  unsigned short* P1t = W1t + (size_t)HH * DD;

  kprep<<<64, 256, 0, stream>>>(q, W1, b1, P1, pb1, W1t, P1t, base1, baseP, normsq);
  kgemm<<<1024, 512, 0, stream>>>(emb, W1t, P1t, base1, baseP, W2, b2, P2, pb2,
                                  buf0, psl);
  applyscale<<<512, 256, 0, stream>>>(buf0, psl, lab, buf1);
  sdiff<<<128, 1024, 0, stream>>>(nbr, buf1, buf2, normsq);
  fout<<<512, 256, 0, stream>>>(buf2, normsq, out);
}

// Round 6
// 408.983 us; speedup vs baseline: 1.1157x; 1.1157x over previous
//
#include <hip/hip_runtime.h>
#include <cstdint>
#include <cstddef>

#define BB 16
#define NN 8192
#define DD 384
#define HH 128
#define KK 8
#define DEG 16

typedef short bf8_t __attribute__((ext_vector_type(8)));
typedef float f4_t __attribute__((ext_vector_type(4)));

typedef const __attribute__((address_space(1))) unsigned char* gcp_t;
typedef __attribute__((address_space(3))) unsigned char* lcp_t;

__device__ __forceinline__ void glds16(const void* g, void* l) {
  __builtin_amdgcn_global_load_lds((gcp_t)g, (lcp_t)l, 16, 0, 0);
}

__device__ __forceinline__ unsigned short f2bf(float f) {
  unsigned int u = __float_as_uint(f);
  u += 0x7FFFu + ((u >> 16) & 1u);   // RNE
  return (unsigned short)(u >> 16);
}

__device__ __forceinline__ bf8_t pack8(float4 f0, float4 f1) {
  union { unsigned short us[8]; bf8_t v; } pk;
  pk.us[0] = f2bf(f0.x); pk.us[1] = f2bf(f0.y);
  pk.us[2] = f2bf(f0.z); pk.us[3] = f2bf(f0.w);
  pk.us[4] = f2bf(f1.x); pk.us[5] = f2bf(f1.y);
  pk.us[6] = f2bf(f1.z); pk.us[7] = f2bf(f1.w);
  return pk.v;
}

// ---------------------------------------------------------------------------
// Kprep: (a) fold q@W[384:,:]+bias into per-batch base vectors;
// (b) transpose+convert W1[:384]/P1[:384] to bf16, stored PRE-SWIZZLED and
// K-sixth'd for global_load_lds staging; (c) zero normsq.
// ---------------------------------------------------------------------------
__global__ __launch_bounds__(256) void kprep(
    const float* __restrict__ q, const float* __restrict__ W1,
    const float* __restrict__ b1, const float* __restrict__ P1,
    const float* __restrict__ pb1,
    unsigned short* __restrict__ W1t, unsigned short* __restrict__ P1t,
    float* __restrict__ base1, float* __restrict__ baseP,
    float* __restrict__ normsq)
{
  int blk = blockIdx.x, t = threadIdx.x;
  if (blk < 32) {
    int b = blk >> 1, net = blk & 1;
    const float* W = (net ? P1 : W1) + (size_t)DD * HH;   // q-half rows
    const float* qb = q + b * DD;
    int h = t & 127, half = t >> 7;
    int d0 = half * 192;
    float a0 = 0.f, a1 = 0.f, a2 = 0.f, a3 = 0.f;
    for (int d = d0; d < d0 + 192; d += 4) {
      a0 = fmaf(qb[d],     W[(size_t)d * HH + h],       a0);
      a1 = fmaf(qb[d + 1], W[(size_t)(d + 1) * HH + h], a1);
      a2 = fmaf(qb[d + 2], W[(size_t)(d + 2) * HH + h], a2);
      a3 = fmaf(qb[d + 3], W[(size_t)(d + 3) * HH + h], a3);
    }
    __shared__ float red[256];
    red[t] = (a0 + a1) + (a2 + a3);
    __syncthreads();
    if (t < 128) {
      float tot = red[t] + red[t + 128] + (net ? pb1[h] : b1[h]);
      (net ? baseP : base1)[b * HH + h] = tot;
    }
  } else {
    int e = (blk - 32) * 3072 + t;   // 32 blocks x 3072 = 2*49152 elems
    for (int it = 0; it < 12; ++it, e += 256) {
      int net = e / 49152;
      int r = e - net * 49152;
      int d = r >> 7;          // 0..383
      int h = r & 127;
      float v = (net ? P1 : W1)[d * HH + h];
      int ph = d >> 6;         // K-sixth 0..5
      int rem = d & 63;
      int cb = rem >> 3, wi = rem & 7;
      int c = cb ^ (h & 7);
      (net ? P1t : W1t)[ph * 8192 + h * 64 + c * 8 + wi] = f2bf(v);
    }
    if (blk == 32 && t < BB) normsq[t] = 0.f;
  }
}

// ---------------------------------------------------------------------------
// Kgemm (unchanged from round 4): K-sixth dbuf staging via global_load_lds,
// depth-1 A prefetch, ~116 total regs under __launch_bounds__(512,4).
// ---------------------------------------------------------------------------
__global__ __launch_bounds__(512, 4) void kgemm(
    const float* __restrict__ emb,
    const unsigned short* __restrict__ W1t, const unsigned short* __restrict__ P1t,
    const float* __restrict__ base1, const float* __restrict__ baseP,
    const float* __restrict__ W2, const float* __restrict__ b2,
    const float* __restrict__ P2, const float* __restrict__ pb2,
    float* __restrict__ rawamps, float* __restrict__ pslogit)
{
  __shared__ __align__(16) unsigned short sB[2][128 * 64];   // 2 x 16 KB
  __shared__ float sW2a[128 * 9];
  __shared__ float sBase[128];
  __shared__ float sP2[128];
  __shared__ float sB2[8];

  const int g = blockIdx.x;
  const int slot = g & 7;
  const int net = (g >> 3) & 1;
  const int wid = (g >> 4) * 8 + slot;       // 0..511
  const int b = wid >> 5;
  const int rowbase = (wid & 31) * 256;

  const int t = threadIdx.x;
  const int w = t >> 6, lane = t & 63, q = lane >> 4, ln = lane & 15;
  const int fl = ln & 7;                     // read-side swizzle key

  const unsigned short* Wsw = net ? P1t : W1t;

  // stage sixth 0 into buffer 0 (2 x 1KB per wave)
  {
    const unsigned short* src = Wsw + w * 512 + lane * 8;
    char* dst = (char*)&sB[0][0] + w * 1024;
    glds16(src,        dst);
    glds16(src + 4096, dst + 8192);
  }
  if (t < 128) sBase[t] = (net ? baseP : base1)[b * HH + t];
  if (net == 0) {
    for (int e = t; e < HH * KK; e += 512) {
      int h = e >> 3, kk = e & 7;
      sW2a[h * 9 + kk] = W2[e];
    }
    if (t < 8) sB2[t] = b2[t];
  } else if (t >= 128 && t < 256) {
    sP2[t - 128] = P2[t - 128];
  }

  const float* ar0 = emb + (size_t)(b * NN + rowbase + w * 32 + ln) * DD + q * 8;
  const float* ar1 = ar0 + (size_t)16 * DD;
  float4 pf[4];
  pf[0] = ((const float4*)ar0)[0]; pf[1] = ((const float4*)ar0)[1];
  pf[2] = ((const float4*)ar1)[0]; pf[3] = ((const float4*)ar1)[1];

  f4_t acc[2][8];
  f4_t zero = {0.f, 0.f, 0.f, 0.f};
#pragma unroll
  for (int i = 0; i < 8; ++i) { acc[0][i] = zero; acc[1][i] = zero; }

  __syncthreads();   // sixth 0 staged (barrier drains vmcnt)

#pragma unroll
  for (int ph = 0; ph < 6; ++ph) {
    if (ph < 5) {    // issue next-sixth staging; in flight across 2 j-steps
      const unsigned short* src = Wsw + (ph + 1) * 8192 + w * 512 + lane * 8;
      char* dst = (char*)&sB[0][0] + ((ph + 1) & 1) * 16384 + w * 1024;
      glds16(src,        dst);
      glds16(src + 4096, dst + 8192);
    }
    const char* bbase = (const char*)&sB[0][0] + (ph & 1) * 16384;
#pragma unroll
    for (int jl = 0; jl < 2; ++jl) {
      const int j = ph * 2 + jl;
      bf8_t af0 = pack8(pf[0], pf[1]);
      bf8_t af1 = pack8(pf[2], pf[3]);
      if (j + 1 < 12) {   // depth-1 A prefetch: j+1 in flight under 16 MFMAs
        const float* p0 = ar0 + (j + 1) * 32;
        const float* p1 = ar1 + (j + 1) * 32;
        pf[0] = ((const float4*)p0)[0]; pf[1] = ((const float4*)p0)[1];
        pf[2] = ((const float4*)p1)[0]; pf[3] = ((const float4*)p1)[1];
      }
      const int cb = jl * 4 + q;
#pragma unroll
      for (int ct = 0; ct < 8; ++ct) {
        const int h = ct * 16 + ln;
        bf8_t bf = *(const bf8_t*)(bbase + h * 128 + ((cb ^ fl) << 4));
        acc[0][ct] = __builtin_amdgcn_mfma_f32_16x16x32_bf16(af0, bf, acc[0][ct], 0, 0, 0);
        acc[1][ct] = __builtin_amdgcn_mfma_f32_16x16x32_bf16(af1, bf, acc[1][ct], 0, 0, 0);
      }
    }
    if (ph < 5) __syncthreads();
  }

  const float pb2v = pb2[0];
#pragma unroll
  for (int grp = 0; grp < 2; ++grp) {
#pragma unroll
    for (int r = 0; r < 4; ++r) {
      const int grow = rowbase + w * 32 + grp * 16 + q * 4 + r;
      if (net == 0) {
        float s[8];
#pragma unroll
        for (int kk = 0; kk < 8; ++kk) s[kk] = 0.f;
#pragma unroll
        for (int ct = 0; ct < 8; ++ct) {
          int col = ct * 16 + ln;
          float h1 = fmaxf(acc[grp][ct][r] + sBase[col], 0.f);
#pragma unroll
          for (int kk = 0; kk < 8; ++kk) s[kk] = fmaf(h1, sW2a[col * 9 + kk], s[kk]);
        }
#pragma unroll
        for (int off = 1; off < 16; off <<= 1)
#pragma unroll
          for (int kk = 0; kk < 8; ++kk) s[kk] += __shfl_xor(s[kk], off, 64);
        if (ln == 0) {
          float4 o0, o1;
          o0.x = s[0] + sB2[0]; o0.y = s[1] + sB2[1];
          o0.z = s[2] + sB2[2]; o0.w = s[3] + sB2[3];
          o1.x = s[4] + sB2[4]; o1.y = s[5] + sB2[5];
          o1.z = s[6] + sB2[6]; o1.w = s[7] + sB2[7];
          float4* dst = (float4*)(rawamps + (size_t)(b * NN + grow) * KK);
          dst[0] = o0; dst[1] = o1;
        }
      } else {
        float ps = 0.f;
#pragma unroll
        for (int ct = 0; ct < 8; ++ct) {
          int col = ct * 16 + ln;
          float hp = fmaxf(acc[grp][ct][r] + sBase[col], 0.f);
          ps = fmaf(hp, sP2[col], ps);
        }
#pragma unroll
        for (int off = 1; off < 16; off <<= 1) ps += __shfl_xor(ps, off, 64);
        if (ln == 0) pslogit[b * NN + grow] = ps + pb2v;
      }
    }
  }
}

// ---------------------------------------------------------------------------
// applyscale: ampsP[k][gnode] = raw[node][k] * (1 + sigmoid(psl) + label),
// k-major float planes (32 KB per (b,k)) — the LDS staging unit for sdiff.
// ---------------------------------------------------------------------------
__global__ __launch_bounds__(256) void applyscale(
    const float* __restrict__ raw, const float* __restrict__ psl,
    const int* __restrict__ lab, float* __restrict__ ampsP)
{
  int node = blockIdx.x * 256 + threadIdx.x;   // global node 0..131071
  float sc = 1.f + 1.f / (1.f + __expf(-psl[node])) + (float)lab[node];
  const float4* r = (const float4*)(raw + (size_t)node * KK);
  float4 v0 = r[0], v1 = r[1];
  const int BN = BB * NN;
  ampsP[0 * BN + node] = v0.x * sc;
  ampsP[1 * BN + node] = v0.y * sc;
  ampsP[2 * BN + node] = v0.z * sc;
  ampsP[3 * BN + node] = v0.w * sc;
  ampsP[4 * BN + node] = v1.x * sc;
  ampsP[5 * BN + node] = v1.y * sc;
  ampsP[6 * BN + node] = v1.z * sc;
  ampsP[7 * BN + node] = v1.w * sc;
}

// ---------------------------------------------------------------------------
// sdiff v2: 3 fused diffusion steps per (batch, k) plane in LDS, with ALL
// neighbor indices PRELOADED INTO REGISTERS once (128 idx/thread = 32 int4,
// statically indexed via full unroll; budget 512 regs/wave at 4 waves/SIMD).
// Round-5 lesson: re-streaming nbr per step exposed ~24 dependent global
// latencies per wave (VALUBusy 0.04%!). Now steps are pure-LDS bursts.
// Block mapping b=g&15, k=g>>4: 16===0 mod 8, so all 8 k-planes of a batch
// land on the same XCD -> nbr preload L2-shared.
// 4 barriers; final step writes u3 plane + norm partial.
// ---------------------------------------------------------------------------
__global__ __launch_bounds__(1024, 4) void sdiff(
    const int* __restrict__ nbr, const float* __restrict__ ampsP,
    float* __restrict__ u3P, float* __restrict__ normsq)
{
  __shared__ float sAmp[NN];   // 32 KB
  __shared__ float sSt[NN];    // 32 KB
  const int g = blockIdx.x;    // 128 blocks
  const int b = g & 15;
  const int k = g >> 4;
  const int t = threadIdx.x;   // 0..1023
  const int BN = BB * NN;

  // stage amps plane (coalesced float4)
  {
    const float4* p4 = (const float4*)(ampsP + (size_t)k * BN + (size_t)b * NN);
    float4* s4 = (float4*)sAmp;
    s4[t] = p4[t];
    s4[t + 1024] = p4[t + 1024];
  }

  // preload ALL neighbor indices for this thread's 8 nodes (32 x int4).
  // Full unroll => static indexing => registers (rule #20).
  const int* nbase = nbr + (size_t)b * NN * DEG;
  int4 qv[8][4];
#pragma unroll
  for (int i = 0; i < 8; ++i) {
    const int4* np = (const int4*)(nbase + (size_t)(i * 1024 + t) * DEG);
    qv[i][0] = np[0]; qv[i][1] = np[1]; qv[i][2] = np[2]; qv[i][3] = np[3];
  }
  __syncthreads();

  float res[8];

#define GSTEP(SRC)                                                         \
  _Pragma("unroll")                                                        \
  for (int i = 0; i < 8; ++i) {                                            \
    float a = SRC[qv[i][0].x] + SRC[qv[i][0].y]                            \
            + SRC[qv[i][0].z] + SRC[qv[i][0].w]                            \
            + SRC[qv[i][1].x] + SRC[qv[i][1].y]                            \
            + SRC[qv[i][1].z] + SRC[qv[i][1].w]                            \
            + SRC[qv[i][2].x] + SRC[qv[i][2].y]                            \
            + SRC[qv[i][2].z] + SRC[qv[i][2].w]                            \
            + SRC[qv[i][3].x] + SRC[qv[i][3].y]                            \
            + SRC[qv[i][3].z] + SRC[qv[i][3].w];                           \
    res[i] = a;                                                            \
  }

  // step 1: u1 = S(amps), m1 = u1*amps (sSt untouched by gathers)
  GSTEP(sAmp)
#pragma unroll
  for (int i = 0; i < 8; ++i) sSt[i * 1024 + t] = res[i] * sAmp[i * 1024 + t];
  __syncthreads();

  // step 2: u2 = S(m1), m2 = u2*amps
  GSTEP(sSt)
  __syncthreads();
#pragma unroll
  for (int i = 0; i < 8; ++i) sSt[i * 1024 + t] = res[i] * sAmp[i * 1024 + t];
  __syncthreads();

  // step 3: u3 = S(m2) -> global plane + norm partial
  GSTEP(sSt)
#undef GSTEP
  float* oplane = u3P + (size_t)k * BN + (size_t)b * NN;
  float ss = 0.f;
#pragma unroll
  for (int i = 0; i < 8; ++i) {
    oplane[i * 1024 + t] = res[i];
    ss = fmaf(res[i], res[i], ss);
  }
#pragma unroll
  for (int o = 1; o < 64; o <<= 1) ss += __shfl_xor(ss, o, 64);
  if ((t & 63) == 0) atomicAdd(&normsq[b], ss);
}

__global__ __launch_bounds__(256) void fout(
    const float* __restrict__ u3P, const float* __restrict__ normsq,
    float* __restrict__ out)
{
  int node = blockIdx.x * 256 + threadIdx.x;   // global node
  float ns = normsq[node >> 13];
  float inv = ns > 0.f ? rsqrtf(ns) : 1.f;
  const int BN = BB * NN;
  float s = fabsf(u3P[0 * BN + node]) + fabsf(u3P[1 * BN + node])
          + fabsf(u3P[2 * BN + node]) + fabsf(u3P[3 * BN + node])
          + fabsf(u3P[4 * BN + node]) + fabsf(u3P[5 * BN + node])
          + fabsf(u3P[6 * BN + node]) + fabsf(u3P[7 * BN + node]);
  out[node] = s * inv;
}

extern "C" void kernel_launch(void* const* d_in, const int* in_sizes, int n_in,
                              void* d_out, int out_size, void* d_ws, size_t ws_size,
                              hipStream_t stream) {
  const float* q   = (const float*)d_in[0];
  const float* emb = (const float*)d_in[1];
  const int*   nbr = (const int*)d_in[2];
  const int*   lab = (const int*)d_in[3];
  const float* W1  = (const float*)d_in[4];
  const float* b1  = (const float*)d_in[5];
  const float* W2  = (const float*)d_in[6];
  const float* b2  = (const float*)d_in[7];
  const float* P1  = (const float*)d_in[8];
  const float* pb1 = (const float*)d_in[9];
  const float* P2  = (const float*)d_in[10];
  const float* pb2 = (const float*)d_in[11];
  float* out = (float*)d_out;

  const size_t NK = (size_t)BB * NN * KK;     // 1,048,576 floats (4 MB)
  float* ws     = (float*)d_ws;
  float* buf0   = ws;                         // raw amps (node-major)
  float* buf1   = buf0 + NK;                  // ampsP (k-major planes)
  float* buf2   = buf1 + NK;                  // u3P (k-major planes)
  float* psl    = buf2 + NK;                  // 131072
  float* base1  = psl + (size_t)BB * NN;
  float* baseP  = base1 + BB * HH;
  float* normsq = baseP + BB * HH;
  unsigned short* W1t = (unsigned short*)(normsq + 16);
  unsigned short* P1t = W1t + (size_t)HH * DD;

  kprep<<<64, 256, 0, stream>>>(q, W1, b1, P1, pb1, W1t, P1t, base1, baseP, normsq);
  kgemm<<<1024, 512, 0, stream>>>(emb, W1t, P1t, base1, baseP, W2, b2, P2, pb2,
                                  buf0, psl);
  applyscale<<<512, 256, 0, stream>>>(buf0, psl, lab, buf1);
  sdiff<<<128, 1024, 0, stream>>>(nbr, buf1, buf2, normsq);
  fout<<<512, 256, 0, stream>>>(buf2, normsq, out);
}